// Round 4
// baseline (479.977 us; speedup 1.0000x reference)
//
#include <hip/hip_runtime.h>
#include <math.h>

// Problem: [16,1,1024,1024] fp32 pred/target -> scalar weighted mean-abs curvature loss.
// R11 = R10 resubmitted verbatim (R10's bench never ran: "MI355X container
// failed twice" = broker infra failure; kernel has no hang path -- no
// spin-waits, every block terminates, finalizer only gathers).
// ---
// R10: fused single-dispatch, CORRECTED. R9 post-mortem: the "(t & 4095)==4095"
// residue trick guarantees one finalizer per launch but NOT that it's the LAST
// block -- with garbage initial ticket v, the finalizer is the block at
// completion position 4095-(v mod 4096), which gathered while ~8% of blocks
// hadn't written (err 8.4e-2 + garbage absmax 468: exact signature). Fix:
// hipMemsetAsync(ticket,0,4,stream) each launch (capture-legal; harness itself
// enqueues memsets), finalizer condition t == NBLOCKS-1 exactly. Visibility:
// store blocksums -> __threadfence (agent release) -> acq_rel fetch_add; the
// finalizer's RMW sits at the end of the release sequence -> all 4096 sums
// visible; gather uses agent-scope relaxed atomic loads (per-XCD L2s not
// cross-coherent, Guideline 16). Gather order = old curv_loss_final exactly
// (bitwise-identical, absmax 0.0).
// Main body = R7 VERBATIM (57-58us, VALUBusy 62%): R8 proved manual load
// pipelining regresses the compiler's full-unroll schedule (58->70us).
// ws_size guard falls back to the proven two-kernel path.
// Workspace: blocksums[4096] floats + uint ticket at byte 16384 (16388 B).

constexpr int IMG_B = 16;
constexpr int IMG_H = 1024;
constexpr int IMG_W = 1024;
constexpr int ROWS  = 16;                      // rows per block
constexpr int BLOCK = 256;                     // 256 threads = 256 columns
constexpr int TILES_X = IMG_W / BLOCK;         // 4
constexpr int TILES_Y = IMG_H / ROWS;          // 64
constexpr int NBLOCKS = IMG_B * TILES_Y * TILES_X;  // 4096
constexpr float EPS = 1e-8f;

// scale constants: p = gx/80, q = gy/80, r = rxx/300, 2s = sxy/200, t = tyy/300
constexpr float A2 = 1.0f / 6400.0f;
constexpr float Bc = 1.0f / 300.0f;
constexpr float C2 = 1.0f / 200.0f;

typedef float f2v __attribute__((ext_vector_type(2)));

__device__ __forceinline__ f2v pk_fma(f2v a, f2v b, f2v c) {
    return __builtin_elementwise_fma(a, b, c);
}

// rolling-window row state, lanes = {pred, target}
struct Rowv { f2v hx, hs, rs; };

// prof/plan true scale; mean2 = 2*mean (weight absorbs the 1/2). Lane-parallel
// over {pred, target}; transcendentals + flat-mask stay per-component.
__device__ __forceinline__ void curv_pair(const Rowv& a, const Rowv& b, const Rowv& c,
                                          f2v& prof, f2v& plan, f2v& mean2)
{
    const f2v A2f = {A2, A2}, Bcf = {Bc, Bc}, C2f = {C2, C2};
    const f2v m3  = {-3.0f, -3.0f}, two = {2.0f, 2.0f};
    const f2v epsf = {EPS, EPS};

    const f2v gx  = pk_fma(two, b.hx, a.hx + c.hx);   // sobel_x (raw)
    const f2v gy  = c.hs - a.hs;                      // sobel_y (raw)
    const f2v tot = (a.rs + c.rs) + b.rs;             // 3x3 sum
    const f2v H   = (a.hs + c.hs) + b.hs;
    const f2v rxx = pk_fma(m3, H - tot, tot);         // k_xx * 3 (raw)
    const f2v tyy = pk_fma(m3, b.rs, tot);            // k_yy * 3 (raw)
    const f2v sxy = a.hx - c.hx;                      // k_xy * 4 (raw)

    const f2v gx2 = gx * gx, gy2 = gy * gy, gxgy = gx * gy;
    const f2v g2  = gx2 + gy2;
    const f2v d1  = A2f * g2;                         // p^2 + q^2
    const f2v od  = d1 + f2v{1.0f, 1.0f};

    f2v rsq_od, sq_d1;                                // per-component transcendentals
    rsq_od.x = __builtin_amdgcn_rsqf(od.x);
    rsq_od.y = __builtin_amdgcn_rsqf(od.y);
    sq_d1.x  = __builtin_amdgcn_sqrtf(d1.x);
    sq_d1.y  = __builtin_amdgcn_sqrtf(d1.y);
    const f2v sq_od = od * rsq_od;                    // sqrt(1+d1)

    const f2v h1    = pk_fma(tyy, gy2, rxx * gx2);
    const f2v h3    = pk_fma(tyy, gx2, rxx * gy2);
    const f2v h2c   = C2f * (sxy * gxgy);
    const f2v nprof = A2f * pk_fma(Bcf, h1,  h2c);    // r*p2+2s*pq+t*q2
    const f2v nplan = A2f * pk_fma(Bcf, h3, -h2c);    // r*q2-2s*pq+t*p2
    const f2v mnum  = pk_fma(Bcf, rxx + tyy, nplan);  // (1+q2)r-2pq*s+(1+p2)t

    const f2v den_p = pk_fma(d1, sq_od, epsf);        // d1*sqrt(1+d1)+EPS
    const f2v den_l = pk_fma(d1, sq_d1, epsf);        // d1^1.5+EPS
    const f2v plprod = den_p * den_l;                 // >=1e-16, no underflow
    f2v rcpPL;
    rcpPL.x = __builtin_amdgcn_rcpf(plprod.x);
    rcpPL.y = __builtin_amdgcn_rcpf(plprod.y);

    prof  = (nprof * den_l) * rcpPL;
    plan  = (nplan * den_p) * rcpPL;
    mean2 = mnum * ((rsq_od * rsq_od) * rsq_od);      // mnum/od^1.5 = 2*mean
    // flat mask per component
    prof.x = (d1.x < EPS) ? 0.0f : prof.x;
    prof.y = (d1.y < EPS) ? 0.0f : prof.y;
    plan.x = (d1.x < EPS) ? 0.0f : plan.x;
    plan.y = (d1.y < EPS) ? 0.0f : plan.y;
}

// shared device body: computes this block's sum (R7 structure verbatim)
__device__ __forceinline__ float block_body(
    const float* __restrict__ pred, const float* __restrict__ targ,
    int b, int tid, float* ws /*LDS, BLOCK/64 floats*/)
{
    const int tx  = b & (TILES_X - 1);
    const int ty  = (b >> 2) & (TILES_Y - 1);
    const int img = b >> 8;                   // 4*64 = 256 blocks per image
    const int y0  = ty * ROWS;
    const int x   = tx * BLOCK + tid;

    const size_t ibase = (size_t)img * (size_t)(IMG_H * IMG_W);
    const char* __restrict__ Pc = (const char*)(pred + ibase);
    const char* __restrict__ Tc = (const char*)(targ + ibase);

    const bool xm = (x > 0);
    const bool xp = (x < IMG_W - 1);
    // per-tap byte offsets within a row (clamped at image edge; value masked to 0)
    const int eL = (x + (xm ? -1 : 0)) << 2;
    const int eC = x << 2;
    const int eR = (x + (xp ? +1 : 0)) << 2;

    // prep one row into the rolling window; vo = row byte offset (y<<12)
    auto prep = [&](int y, Rowv& o) {
        if ((unsigned)y < (unsigned)IMG_H) {          // block-uniform branch
            const int vo = y << 12;
            const float pl = *(const float*)(Pc + vo + eL);
            const float tl = *(const float*)(Tc + vo + eL);
            const float pc = *(const float*)(Pc + vo + eC);
            const float tc = *(const float*)(Tc + vo + eC);
            const float pr = *(const float*)(Pc + vo + eR);
            const float tr = *(const float*)(Tc + vo + eR);
            const f2v w0 = {xm ? pl : 0.0f, xm ? tl : 0.0f};
            const f2v w1 = {pc, tc};
            const f2v w2 = {xp ? pr : 0.0f, xp ? tr : 0.0f};
            const f2v e = w0 + w2;
            o.hx = w2 - w0;
            o.hs = pk_fma(f2v{2.0f, 2.0f}, w1, e);
            o.rs = e + w1;
        } else {                                       // zero 'SAME' padding row
            o.hx = f2v{0.0f, 0.0f}; o.hs = f2v{0.0f, 0.0f}; o.rs = f2v{0.0f, 0.0f};
        }
    };

    Rowv w[3];
    prep(y0 - 1, w[0]);
    prep(y0,     w[1]);

    float acc = 0.0f;
#pragma unroll
    for (int i = 0; i < ROWS; ++i) {
        const int ia = i % 3, ib = (i + 1) % 3, ic = (i + 2) % 3;
        prep(y0 + i + 1, w[ic]);
        f2v prof, plan, mean2;
        curv_pair(w[ia], w[ib], w[ic], prof, plan, mean2);
        acc = fmaf(0.5f, fabsf(prof.x  - prof.y),  acc);
        acc = fmaf(0.3f, fabsf(plan.x  - plan.y),  acc);
        acc = fmaf(0.1f, fabsf(mean2.x - mean2.y), acc);  // 0.2*|dMean|
    }

    // wave64 reduce, then cross-wave via LDS
#pragma unroll
    for (int off = 32; off > 0; off >>= 1) acc += __shfl_down(acc, off, 64);
    const int lane = tid & 63, wid = tid >> 6;
    if (lane == 0) ws[wid] = acc;
    __syncthreads();
    return (ws[0] + ws[1]) + (ws[2] + ws[3]);   // valid in all threads
}

// ---------------- fused single-dispatch path ----------------
__global__ __launch_bounds__(BLOCK) void curv_loss_fused(
    const float* __restrict__ pred, const float* __restrict__ targ,
    float* __restrict__ blocksums, unsigned int* __restrict__ ticket,
    float* __restrict__ out)
{
    const int tid = threadIdx.x;
    const int b   = blockIdx.x;
    __shared__ float ws[BLOCK / 64];
    __shared__ int last_flag;

    const float bsum = block_body(pred, targ, b, tid, ws);

    if (tid == 0) {
        blocksums[b] = bsum;
        __threadfence();                               // release blocksums[b] (agent scope)
        const unsigned int t = __hip_atomic_fetch_add(
            ticket, 1u, __ATOMIC_ACQ_REL, __HIP_MEMORY_SCOPE_AGENT);
        last_flag = (t == (unsigned)(NBLOCKS - 1));    // ticket memset to 0 per launch
    }
    __syncthreads();
    if (!last_flag) return;

    // ---- final reduce, order identical to the two-kernel curv_loss_final ----
    float v = 0.0f;
#pragma unroll
    for (int i = 0; i < NBLOCKS / BLOCK; ++i)
        v += __hip_atomic_load(&blocksums[i * BLOCK + tid],
                               __ATOMIC_RELAXED, __HIP_MEMORY_SCOPE_AGENT);
#pragma unroll
    for (int off = 32; off > 0; off >>= 1) v += __shfl_down(v, off, 64);
    const int lane = tid & 63, wid = tid >> 6;
    if (lane == 0) ws[wid] = v;        // safe: all earlier ws reads precede the
    __syncthreads();                   // last_flag __syncthreads above
    if (tid == 0) {
        const float tot = (ws[0] + ws[1]) + (ws[2] + ws[3]);
        out[0] = tot * (1.0f / (float)(IMG_B * IMG_H * IMG_W));
    }
}

// ---------------- two-kernel fallback (proven R7 path) ----------------
__global__ __launch_bounds__(BLOCK) void curv_loss_main(
    const float* __restrict__ pred, const float* __restrict__ targ,
    float* __restrict__ blocksums)
{
    const int tid = threadIdx.x;
    const int b   = blockIdx.x;
    __shared__ float ws[BLOCK / 64];
    const float bsum = block_body(pred, targ, b, tid, ws);
    if (tid == 0) blocksums[b] = bsum;
}

__global__ __launch_bounds__(BLOCK) void curv_loss_final(
    const float* __restrict__ blocksums, float* __restrict__ out)
{
    const int tid = threadIdx.x;
    float v = 0.0f;
#pragma unroll
    for (int i = 0; i < NBLOCKS / BLOCK; ++i) v += blocksums[i * BLOCK + tid];
#pragma unroll
    for (int off = 32; off > 0; off >>= 1) v += __shfl_down(v, off, 64);
    __shared__ float ws[BLOCK / 64];
    const int lane = tid & 63, wid = tid >> 6;
    if (lane == 0) ws[wid] = v;
    __syncthreads();
    if (tid == 0) {
        const float tot = (ws[0] + ws[1]) + (ws[2] + ws[3]);
        out[0] = tot * (1.0f / (float)(IMG_B * IMG_H * IMG_W));
    }
}

extern "C" void kernel_launch(void* const* d_in, const int* in_sizes, int n_in,
                              void* d_out, int out_size, void* d_ws, size_t ws_size,
                              hipStream_t stream)
{
    const float* pred = (const float*)d_in[0];
    const float* targ = (const float*)d_in[1];
    float* out = (float*)d_out;
    float* blocksums = (float*)d_ws;                   // 4096 floats
    unsigned int* ticket = (unsigned int*)((char*)d_ws + NBLOCKS * sizeof(float));

    if (ws_size >= (size_t)(NBLOCKS * sizeof(float) + sizeof(unsigned int))) {
        // reset ticket each launch: finalizer condition t == NBLOCKS-1 is exact
        hipMemsetAsync(ticket, 0, sizeof(unsigned int), stream);
        curv_loss_fused<<<NBLOCKS, BLOCK, 0, stream>>>(pred, targ, blocksums, ticket, out);
    } else {
        curv_loss_main<<<NBLOCKS, BLOCK, 0, stream>>>(pred, targ, blocksums);
        curv_loss_final<<<1, BLOCK, 0, stream>>>(blocksums, out);
    }
}

// Round 5
// 186.197 us; speedup vs baseline: 2.5778x; 2.5778x over previous
//
#include <hip/hip_runtime.h>
#include <math.h>

// Problem: [16,1,1024,1024] fp32 pred/target -> scalar weighted mean-abs curvature loss.
// R12: revert fusion (R11: per-block agent-scope __threadfence + acq_rel RMW
// compile to L2 writeback + L1/L2 invalidate on CDNA4 -- 4096 blocks wiped all
// 8 XCD L2s continuously; VALUBusy 62->9.5%, 58->373us. NEVER put device-scope
// fences/atomics in the per-block path of a cache-reliant kernel). Two-kernel
// structure restored; ~90us of dur_us outside main is harness-fixed overhead.
// Main-kernel change: 4 columns/thread via aligned float4 loads. R7 issued 6
// scalar loads per thread-row (each cacheline fetched 3x by neighbor lanes;
// 108 VMEM/thread = the latency events behind the 38% idle). Now per row per
// image: 1 dwordx4 + 2 scalar halo = 3 VMEM for 4 cols (8x fewer per pixel),
// 16B/lane coalescing, and 4 independent column pipelines of ILP per wave.
// Block = 256 thr x 4 cols = full 1024-wide row; grid 1024 blocks (4/CU).
// Per-pixel math = R7 exactly (same ops, same order, same EPS); only the
// reduction grouping changes (threshold 2.8e-3).

constexpr int IMG_B = 16;
constexpr int IMG_H = 1024;
constexpr int IMG_W = 1024;
constexpr int ROWS  = 16;                      // rows per block
constexpr int BLOCK = 256;                     // threads; x4 cols = full row
constexpr int COLS  = 4;                       // columns per thread
constexpr int TILES_Y = IMG_H / ROWS;          // 64
constexpr int NBLOCKS = IMG_B * TILES_Y;       // 1024
constexpr float EPS = 1e-8f;

// scale constants: p = gx/80, q = gy/80, r = rxx/300, 2s = sxy/200, t = tyy/300
constexpr float A2 = 1.0f / 6400.0f;
constexpr float Bc = 1.0f / 300.0f;
constexpr float C2 = 1.0f / 200.0f;

typedef float f2v __attribute__((ext_vector_type(2)));
typedef float f4v __attribute__((ext_vector_type(4)));

__device__ __forceinline__ f2v pk_fma(f2v a, f2v b, f2v c) {
    return __builtin_elementwise_fma(a, b, c);
}

// rolling-window row state for ONE column, lanes = {pred, target}
struct Rowv { f2v hx, hs, rs; };
// rolling-window row state for the thread's 4 columns
struct Rowv4 { f2v hx[COLS], hs[COLS], rs[COLS]; };

// prof/plan true scale; mean2 = 2*mean (weight absorbs the 1/2). Lane-parallel
// over {pred, target}; transcendentals + flat-mask stay per-component.
__device__ __forceinline__ void curv_pair(const Rowv& a, const Rowv& b, const Rowv& c,
                                          f2v& prof, f2v& plan, f2v& mean2)
{
    const f2v A2f = {A2, A2}, Bcf = {Bc, Bc}, C2f = {C2, C2};
    const f2v m3  = {-3.0f, -3.0f}, two = {2.0f, 2.0f};
    const f2v epsf = {EPS, EPS};

    const f2v gx  = pk_fma(two, b.hx, a.hx + c.hx);   // sobel_x (raw)
    const f2v gy  = c.hs - a.hs;                      // sobel_y (raw)
    const f2v tot = (a.rs + c.rs) + b.rs;             // 3x3 sum
    const f2v H   = (a.hs + c.hs) + b.hs;
    const f2v rxx = pk_fma(m3, H - tot, tot);         // k_xx * 3 (raw)
    const f2v tyy = pk_fma(m3, b.rs, tot);            // k_yy * 3 (raw)
    const f2v sxy = a.hx - c.hx;                      // k_xy * 4 (raw)

    const f2v gx2 = gx * gx, gy2 = gy * gy, gxgy = gx * gy;
    const f2v g2  = gx2 + gy2;
    const f2v d1  = A2f * g2;                         // p^2 + q^2
    const f2v od  = d1 + f2v{1.0f, 1.0f};

    f2v rsq_od, sq_d1;                                // per-component transcendentals
    rsq_od.x = __builtin_amdgcn_rsqf(od.x);
    rsq_od.y = __builtin_amdgcn_rsqf(od.y);
    sq_d1.x  = __builtin_amdgcn_sqrtf(d1.x);
    sq_d1.y  = __builtin_amdgcn_sqrtf(d1.y);
    const f2v sq_od = od * rsq_od;                    // sqrt(1+d1)

    const f2v h1    = pk_fma(tyy, gy2, rxx * gx2);
    const f2v h3    = pk_fma(tyy, gx2, rxx * gy2);
    const f2v h2c   = C2f * (sxy * gxgy);
    const f2v nprof = A2f * pk_fma(Bcf, h1,  h2c);    // r*p2+2s*pq+t*q2
    const f2v nplan = A2f * pk_fma(Bcf, h3, -h2c);    // r*q2-2s*pq+t*p2
    const f2v mnum  = pk_fma(Bcf, rxx + tyy, nplan);  // (1+q2)r-2pq*s+(1+p2)t

    const f2v den_p = pk_fma(d1, sq_od, epsf);        // d1*sqrt(1+d1)+EPS
    const f2v den_l = pk_fma(d1, sq_d1, epsf);        // d1^1.5+EPS
    const f2v plprod = den_p * den_l;                 // >=1e-16, no underflow
    f2v rcpPL;
    rcpPL.x = __builtin_amdgcn_rcpf(plprod.x);
    rcpPL.y = __builtin_amdgcn_rcpf(plprod.y);

    prof  = (nprof * den_l) * rcpPL;
    plan  = (nplan * den_p) * rcpPL;
    mean2 = mnum * ((rsq_od * rsq_od) * rsq_od);      // mnum/od^1.5 = 2*mean
    // flat mask per component
    prof.x = (d1.x < EPS) ? 0.0f : prof.x;
    prof.y = (d1.y < EPS) ? 0.0f : prof.y;
    plan.x = (d1.x < EPS) ? 0.0f : plan.x;
    plan.y = (d1.y < EPS) ? 0.0f : plan.y;
}

__global__ __launch_bounds__(BLOCK) void curv_loss_main(
    const float* __restrict__ pred, const float* __restrict__ targ,
    float* __restrict__ blocksums)
{
    const int tid = threadIdx.x;
    const int b   = blockIdx.x;
    const int ty  = b & (TILES_Y - 1);
    const int img = b >> 6;                   // 64 blocks per image
    const int y0  = ty * ROWS;

    const size_t ibase = (size_t)img * (size_t)(IMG_H * IMG_W);
    const char* __restrict__ Pc = (const char*)(pred + ibase);
    const char* __restrict__ Tc = (const char*)(targ + ibase);

    const bool xm = (tid > 0);                // left halo valid (col x0-1 >= 0)
    const bool xp = (tid < BLOCK - 1);        // right halo valid (col x0+4 <= 1023)
    const int eC = tid << 4;                  // byte offset of this thread's float4
    const int eM = xm ? (eC - 4)  : eC;       // clamped left-halo byte offset
    const int eP = xp ? (eC + 16) : (eC + 12);// clamped right-halo byte offset

    // prep one row into the rolling window; vo = row byte offset (y<<12).
    // R7 structure: load+combine together, full unroll; the compiler's own
    // cross-iteration load clustering beats manual pipelining (R8 evidence).
    auto prep = [&](int y, Rowv4& o) {
        if ((unsigned)y < (unsigned)IMG_H) {          // block-uniform branch
            const int vo = y << 12;
            const f4v pv = *(const f4v*)(Pc + vo + eC);   // 16B aligned
            const f4v tv = *(const f4v*)(Tc + vo + eC);
            const float pm = *(const float*)(Pc + vo + eM);
            const float tm = *(const float*)(Tc + vo + eM);
            const float pp = *(const float*)(Pc + vo + eP);
            const float tp = *(const float*)(Tc + vo + eP);
            f2v win[COLS + 2];                 // static-indexed under unroll
            win[0] = f2v{xm ? pm : 0.0f, xm ? tm : 0.0f};
            win[1] = f2v{pv.x, tv.x};
            win[2] = f2v{pv.y, tv.y};
            win[3] = f2v{pv.z, tv.z};
            win[4] = f2v{pv.w, tv.w};
            win[5] = f2v{xp ? pp : 0.0f, xp ? tp : 0.0f};
#pragma unroll
            for (int j = 0; j < COLS; ++j) {
                const f2v w0 = win[j], w1 = win[j + 1], w2 = win[j + 2];
                const f2v e = w0 + w2;
                o.hx[j] = w2 - w0;
                o.hs[j] = pk_fma(f2v{2.0f, 2.0f}, w1, e);
                o.rs[j] = e + w1;
            }
        } else {                               // zero 'SAME' padding row
#pragma unroll
            for (int j = 0; j < COLS; ++j) {
                o.hx[j] = f2v{0.0f, 0.0f};
                o.hs[j] = f2v{0.0f, 0.0f};
                o.rs[j] = f2v{0.0f, 0.0f};
            }
        }
    };

    Rowv4 w[3];
    prep(y0 - 1, w[0]);
    prep(y0,     w[1]);

    float acc = 0.0f;
#pragma unroll
    for (int i = 0; i < ROWS; ++i) {
        const int ia = i % 3, ib = (i + 1) % 3, ic = (i + 2) % 3;
        prep(y0 + i + 1, w[ic]);
#pragma unroll
        for (int j = 0; j < COLS; ++j) {
            const Rowv a{w[ia].hx[j], w[ia].hs[j], w[ia].rs[j]};
            const Rowv bb{w[ib].hx[j], w[ib].hs[j], w[ib].rs[j]};
            const Rowv c{w[ic].hx[j], w[ic].hs[j], w[ic].rs[j]};
            f2v prof, plan, mean2;
            curv_pair(a, bb, c, prof, plan, mean2);
            acc = fmaf(0.5f, fabsf(prof.x  - prof.y),  acc);
            acc = fmaf(0.3f, fabsf(plan.x  - plan.y),  acc);
            acc = fmaf(0.1f, fabsf(mean2.x - mean2.y), acc);  // 0.2*|dMean|
        }
    }

    // wave64 reduce, then cross-wave via LDS
#pragma unroll
    for (int off = 32; off > 0; off >>= 1) acc += __shfl_down(acc, off, 64);
    __shared__ float ws[BLOCK / 64];
    const int lane = tid & 63, wid = tid >> 6;
    if (lane == 0) ws[wid] = acc;
    __syncthreads();
    if (tid == 0)
        blocksums[b] = (ws[0] + ws[1]) + (ws[2] + ws[3]);
}

__global__ __launch_bounds__(BLOCK) void curv_loss_final(
    const float* __restrict__ blocksums, float* __restrict__ out)
{
    const int tid = threadIdx.x;
    float v = 0.0f;
#pragma unroll
    for (int i = 0; i < NBLOCKS / BLOCK; ++i) v += blocksums[i * BLOCK + tid];
#pragma unroll
    for (int off = 32; off > 0; off >>= 1) v += __shfl_down(v, off, 64);
    __shared__ float ws[BLOCK / 64];
    const int lane = tid & 63, wid = tid >> 6;
    if (lane == 0) ws[wid] = v;
    __syncthreads();
    if (tid == 0) {
        const float tot = (ws[0] + ws[1]) + (ws[2] + ws[3]);
        out[0] = tot * (1.0f / (float)(IMG_B * IMG_H * IMG_W));
    }
}

extern "C" void kernel_launch(void* const* d_in, const int* in_sizes, int n_in,
                              void* d_out, int out_size, void* d_ws, size_t ws_size,
                              hipStream_t stream)
{
    const float* pred = (const float*)d_in[0];
    const float* targ = (const float*)d_in[1];
    float* out = (float*)d_out;
    float* blocksums = (float*)d_ws;   // 1024 floats; every slot written each call

    curv_loss_main<<<NBLOCKS, BLOCK, 0, stream>>>(pred, targ, blocksums);
    curv_loss_final<<<1, BLOCK, 0, stream>>>(blocksums, out);
}